// Round 1
// 407.619 us; speedup vs baseline: 1.0708x; 1.0708x over previous
//
#include <hip/hip_runtime.h>

// Problem constants (match reference setup_inputs)
#define B_   1024
#define C_   200
#define L_   3
#define DIM_ 512
#define S_   (C_ + 1)   // 201 output rows per batch

// Batch-group design: one 256-thread block owns one channel c and NB_ batches.
// 128 lanes cover DIM_ as float4; tid>>7 picks one of 2 concurrent batches;
// an unrolled loop of NB_/2 iterations covers the rest. W row + pe row are
// loaded ONCE per block and reused for all NB_ output rows.
#define NB_       16
#define NGRP_     (B_ / NB_)        // 64 batch groups
#define NBLK_C_   (C_ * NGRP_)      // 12800 conv blocks
#define NBLK_CLS_ NGRP_             // 64 cls blocks

typedef float f4 __attribute__((ext_vector_type(4)));

__global__ __launch_bounds__(256) void GSE_84722524880902_kernel(
    const float* __restrict__ x,        // [B, C]
    const float* __restrict__ W,        // [C, L, DIM]
    const float* __restrict__ cls_tok,  // [1, 1, DIM]
    const float* __restrict__ pe,       // [C+1, DIM]
    float* __restrict__ out)            // [B, C+1, DIM]
{
    const int lane = threadIdx.x & 127;   // float4 lane over DIM_
    const int bsub = threadIdx.x >> 7;    // 0/1: two batches in flight
    const int d    = lane << 2;
    const int blk  = blockIdx.x;

    if (blk < NBLK_C_) {
        // c fast-varying across blocks: consecutive blocks write consecutive
        // output rows within a batch and read overlapping x cache lines.
        const int c  = blk % C_;
        const int bg = blk / C_;
        const int b0 = bg * NB_ + bsub;
        const int s  = c + 1;

        // edge-replicate pad: window indices clamp into [0, C-1]
        const int cm = (c > 0)      ? c - 1 : 0;
        const int cp = (c < C_ - 1) ? c + 1 : C_ - 1;

        // Hoisted per-block context: pe row + 3 W sub-rows (reused NB_ times)
        const f4 pev = *(const f4*)(pe + s * DIM_ + d);
        const float* wrow = W + c * (L_ * DIM_) + d;
        const f4 a0 = *(const f4*)(wrow + 0 * DIM_);
        const f4 a1 = *(const f4*)(wrow + 1 * DIM_);
        const f4 a2 = *(const f4*)(wrow + 2 * DIM_);

        const float* xb = x + b0 * C_;
        f4* op = (f4*)(out + (b0 * S_ + s) * DIM_) + lane;

        #pragma unroll
        for (int i = 0; i < NB_ / 2; ++i) {
            // wave-uniform scalar loads (L2-resident, broadcast)
            const float w0 = xb[cm];
            const float w1 = xb[c];
            const float w2 = xb[cp];
            f4 r;
            r.x = fmaf(w0, a0.x, fmaf(w1, a1.x, fmaf(w2, a2.x, pev.x)));
            r.y = fmaf(w0, a0.y, fmaf(w1, a1.y, fmaf(w2, a2.y, pev.y)));
            r.z = fmaf(w0, a0.z, fmaf(w1, a1.z, fmaf(w2, a2.z, pev.z)));
            r.w = fmaf(w0, a0.w, fmaf(w1, a1.w, fmaf(w2, a2.w, pev.w)));
            // streaming store: output is write-once, keep it out of L2
            __builtin_nontemporal_store(r, op);
            xb += 2 * C_;                 // advance 2 batches
            op += 2 * S_ * (DIM_ / 4);
        }
    } else {
        // cls rows: out[b, 0, :] = cls_token + pe[0]  (same value for all b)
        const int bg = blk - NBLK_C_;
        const int b0 = bg * NB_ + bsub;

        const f4 pev = *(const f4*)(pe + d);
        const f4 cv  = *(const f4*)(cls_tok + d);
        f4 r;
        r.x = cv.x + pev.x;
        r.y = cv.y + pev.y;
        r.z = cv.z + pev.z;
        r.w = cv.w + pev.w;

        f4* op = (f4*)(out + b0 * S_ * DIM_) + lane;
        #pragma unroll
        for (int i = 0; i < NB_ / 2; ++i) {
            __builtin_nontemporal_store(r, op);
            op += 2 * S_ * (DIM_ / 4);
        }
    }
}

extern "C" void kernel_launch(void* const* d_in, const int* in_sizes, int n_in,
                              void* d_out, int out_size, void* d_ws, size_t ws_size,
                              hipStream_t stream) {
    const float* x       = (const float*)d_in[0];   // [B, C]
    const float* W       = (const float*)d_in[1];   // [C, L, DIM]
    const float* cls_tok = (const float*)d_in[2];   // [1, 1, DIM]
    const float* pe      = (const float*)d_in[3];   // [C+1, DIM]
    float* out           = (float*)d_out;           // [B, C+1, DIM]

    const int grid = NBLK_C_ + NBLK_CLS_;           // 12864 blocks of 256
    GSE_84722524880902_kernel<<<grid, 256, 0, stream>>>(x, W, cls_tok, pe, out);
}